// Round 13
// baseline (225.963 us; speedup 1.0000x reference)
//
#include <hip/hip_runtime.h>
#include <cstdint>
#include <cstddef>

// ---------------------------------------------------------------------------
// GCN encoder:
//   g[u]  = dinv[u] * h[u]    (folded into GEMM epilogue, bf16, SLICE-MAJOR)
//   out[v]= dinv[v] * (sum_{e:dst=v} g[src] + g[v]) + b
// r13: CSR build restructured — unordered region allocation via one
// atomicAdd per node (k_alloc, int2 {start,end}) replaces the 3-kernel
// prefix scan; deg/flag/gcnt init folded into k_prep; detect reads odd
// words only. 9 launches (was 11). Aggregates unchanged: measured at
// ~7 TB/s gather service across r3-r12 variants = data-movement roofline.
// ---------------------------------------------------------------------------

static constexpr int CH1 = 256;
static constexpr int CH2 = 128;

typedef __attribute__((ext_vector_type(8))) short bf16x8;
typedef __attribute__((ext_vector_type(4))) float f32x4;
typedef __attribute__((ext_vector_type(8))) unsigned short u16x8;

__device__ inline unsigned short f2bf(float f) {  // round-to-nearest-even
  unsigned u = __builtin_bit_cast(unsigned, f);
  return (unsigned short)((u + 0x7fffu + ((u >> 16) & 1u)) >> 16);
}

__device__ inline void gload16(const void* g, void* l) {
  __builtin_amdgcn_global_load_lds(
      (const __attribute__((address_space(1))) unsigned int*)g,
      (__attribute__((address_space(3))) unsigned int*)l, 16, 0, 0);
}

// ---------------- fused prep -----------------------------------------------
// i < n8x:   x fp32 -> bf16 (8 elems/thread)
// then W1 -> W1^T bf16, W2 -> W2^T bf16 (element ranges)
// i < N:     deg[i] = 0
// i == 0:    flag = 0, gcnt = 0
__global__ void k_prep(const float4* __restrict__ x, u16x8* __restrict__ xo, int n8x,
                       const float* __restrict__ W1, unsigned short* __restrict__ w1t,
                       int Ka, int Na,
                       const float* __restrict__ W2, unsigned short* __restrict__ w2t,
                       int Kb, int Nb,
                       int* __restrict__ deg, int N,
                       int* __restrict__ flag, int* __restrict__ gcnt) {
  int i = blockIdx.x * blockDim.x + threadIdx.x;
  if (i == 0) { *flag = 0; *gcnt = 0; }
  if (i < N) deg[i] = 0;
  if (i < n8x) {
    float4 a = x[i * 2], b = x[i * 2 + 1];
    u16x8 p;
    p[0] = f2bf(a.x); p[1] = f2bf(a.y); p[2] = f2bf(a.z); p[3] = f2bf(a.w);
    p[4] = f2bf(b.x); p[5] = f2bf(b.y); p[6] = f2bf(b.z); p[7] = f2bf(b.w);
    xo[i] = p;
    return;
  }
  int j = i - n8x;
  if (j < Ka * Na) {
    int k = j / Na, n = j - k * Na;
    w1t[(size_t)n * Ka + k] = f2bf(W1[j]);
    return;
  }
  j -= Ka * Na;
  if (j < Kb * Nb) {
    int k = j / Nb, n = j - k * Nb;
    w2t[(size_t)n * Kb + k] = f2bf(W2[j]);
  }
}

// int64 vs int32 layout probe: odd 32-bit words are all 0 iff int64 (<2^32).
__global__ void k_detect_i32(const unsigned int* __restrict__ w, int E,
                             int* __restrict__ flag) {
  int i = blockIdx.x * blockDim.x + threadIdx.x;
  if (i < E && w[2 * i + 1] != 0u) *flag = 1;
}

// fused convert + degree count (deg zeroed in k_prep)
__global__ void k_cvt_deg(const void* __restrict__ raw, int* __restrict__ e32,
                          int* __restrict__ deg, int E, const int* __restrict__ flag) {
  int i = blockIdx.x * blockDim.x + threadIdx.x;
  if (i >= 2 * E) return;
  int v = (*flag) ? ((const int*)raw)[i] : (int)((const long long*)raw)[i];
  e32[i] = v;
  if (i >= E) atomicAdd(&deg[v], 1);  // dst half
}

// Unordered CSR region allocation: one atomicAdd per node (wave-aggregated).
// Region order is call-nondeterministic; aggregate results are order-free.
__global__ void k_alloc(const int* __restrict__ deg, int2* __restrict__ rowse,
                        int* __restrict__ cursor, float* __restrict__ dinv,
                        int* __restrict__ gcnt, int N) {
  int v = blockIdx.x * blockDim.x + threadIdx.x;
  if (v >= N) return;
  int d = deg[v];
  int rs = atomicAdd(gcnt, d);
  rowse[v] = make_int2(rs, rs + d);
  cursor[v] = rs;
  dinv[v] = rsqrtf((float)(d + 1));  // +1: self-loop
}

__global__ void k_fill(const int* __restrict__ src, const int* __restrict__ dst,
                       int* __restrict__ cursor, int* __restrict__ csr, int E) {
  int e = blockIdx.x * blockDim.x + threadIdx.x;
  if (e < E) {
    int pos = atomicAdd(&cursor[dst[e]], 1);
    csr[pos] = src[e];
  }
}

// ---------------------------------------------------------------------------
// bf16 MFMA GEMM: C[M,BN] = A[M,K] @ B[K,BN]. BM=128, 512 thr / 8 waves
// (2M x 4N). A row-major bf16, B as B^T bf16 [BN,K]. fp32 accum.
// Epilogue: g = dinv[row]*acc, bf16 SLICE-MAJOR 64ch:
// Co[(col/64)*M*64 + row*64 + col%64].
// LDS double-buffered, global_load_lds 16B staging, 16B-slot XOR swizzle.
// ---------------------------------------------------------------------------
template <int BN>
__global__ __launch_bounds__(512) void k_gemm_mfma(
    const unsigned short* __restrict__ A, const unsigned short* __restrict__ Bt,
    const float* __restrict__ dinv, unsigned short* __restrict__ Co, int M, int K) {
  constexpr int BM = 128, BK = 32;
  constexpr int NF = BN / 64;          // B frags per wave (4 or 2)
  constexpr int ASZ = BM * BK;         // 4096 ushorts
  constexpr int BSZ = BN * BK;
  __shared__ unsigned short lds[2][ASZ + BSZ];
  const int t = threadIdx.x;
  const int w = t >> 6, l = t & 63;
  const int wm = w >> 2, wn = w & 3;   // 2 x 4 wave grid
  const int m0 = blockIdx.x * BM;
  const int lr = l & 15, lk = l >> 4;

  auto stage = [&](int buf, int k0) {
    unsigned short* base = lds[buf];
    {  // A: 512 slots, one per thread
      int row = t >> 2, p = t & 3;
      int s = p ^ ((row >> 1) & 3);
      int gm = m0 + row; if (gm >= M) gm = M - 1;
      gload16(A + (size_t)gm * K + k0 + s * 8, base + (size_t)row * BK + p * 8);
    }
    for (int i = t; i < BN * 4; i += 512) {  // B: BN*4 slots
      int n = i >> 2, p = i & 3;
      int s = p ^ ((n >> 1) & 3);
      gload16(Bt + (size_t)n * K + k0 + s * 8, base + ASZ + (size_t)n * BK + p * 8);
    }
  };

  f32x4 acc[4][NF];
#pragma unroll
  for (int a = 0; a < 4; ++a)
#pragma unroll
    for (int b = 0; b < NF; ++b) acc[a][b] = (f32x4){0.f, 0.f, 0.f, 0.f};

  stage(0, 0);
  __syncthreads();
  const int nsteps = K / BK;
  for (int ks = 0; ks < nsteps; ++ks) {
    int cur = ks & 1;
    if (ks + 1 < nsteps) stage(cur ^ 1, (ks + 1) * BK);
    const unsigned short* base = lds[cur];
    bf16x8 ah[4], bh[NF];
#pragma unroll
    for (int fm = 0; fm < 4; ++fm) {
      int row = wm * 64 + fm * 16 + lr;
      int p = lk ^ ((row >> 1) & 3);
      ah[fm] = *(const bf16x8*)(base + row * BK + p * 8);
    }
#pragma unroll
    for (int fb = 0; fb < NF; ++fb) {
      int n = wn * (BN / 4) + fb * 16 + lr;
      int p = lk ^ ((n >> 1) & 3);
      bh[fb] = *(const bf16x8*)(base + ASZ + n * BK + p * 8);
    }
#pragma unroll
    for (int fm = 0; fm < 4; ++fm)
#pragma unroll
      for (int fb = 0; fb < NF; ++fb)
        acc[fm][fb] = __builtin_amdgcn_mfma_f32_16x16x32_bf16(ah[fm], bh[fb], acc[fm][fb], 0, 0, 0);
    __syncthreads();
  }
  // epilogue: C/D layout col=lane&15, row=(lane>>4)*4+reg; g=dinv*acc, sliced
#pragma unroll
  for (int fm = 0; fm < 4; ++fm)
#pragma unroll
    for (int r = 0; r < 4; ++r) {
      int row = m0 + wm * 64 + fm * 16 + lk * 4 + r;
      if (row < M) {
        float dv = dinv[row];
#pragma unroll
        for (int fb = 0; fb < NF; ++fb) {
          int col = wn * (BN / 4) + fb * 16 + lr;
          size_t o = ((size_t)(col >> 6) * M + row) * 64 + (col & 63);
          Co[o] = f2bf(dv * acc[fm][fb][r]);
        }
      }
    }
}

// ---------------------------------------------------------------------------
// Persistent slice-resident gather-aggregate over pre-scaled bf16 gS (64-ch
// slices, 128B rows). Fixed grid; block keeps one slice (x=bid&7 ->
// XCD-L2 affinity) and grid-strides over node-groups of 8.
// 32 lanes/node: 4 sub-lanes (stride-4 edges) x 8 channel lanes (uint4).
// v_dot2_f32_bf16 accum. out = dinv[v]*(sum g[src] + g[v]) + b.
// MODE 0: fp32 out.  MODE 1: relu -> bf16 f1.
// ---------------------------------------------------------------------------
template <int C, int MODE>
__global__ __launch_bounds__(256) void k_agg_slice(
    const int2* __restrict__ rowse, const int* __restrict__ csr,
    const float* __restrict__ dinv, const unsigned short* __restrict__ gS,
    const float* __restrict__ bias, float* __restrict__ out,
    unsigned short* __restrict__ of1, int N, int nodeblocks) {
  constexpr int NSL = C / 64;        // 4 (C=256) or 2 (C=128)
  constexpr int DUP = 8 / NSL;       // XCD duplicates per slice
  const int x = blockIdx.x & 7;
  const int slice = x & (NSL - 1);
  const int dup = x >> (NSL == 4 ? 2 : 1);
  const int bstride = ((int)gridDim.x >> 3) * DUP;
  const int ln = threadIdx.x & 31;
  const int sub = ln >> 3;   // edge sub-stream 0..3
  const int l8 = ln & 7;     // channel octet 0..7
  const unsigned short* __restrict__ base = gS + (size_t)slice * N * 64 + l8 * 8;
  const int c0 = slice * 64 + l8 * 8;
  const float4 bA = *(const float4*)(bias + c0);      // invariant per block
  const float4 bB = *(const float4*)(bias + c0 + 4);

  const unsigned selL = 0x00003f80u;  // bf16 pair (lo=1.0, hi=0.0)
  const unsigned selH = 0x3f800000u;  // bf16 pair (lo=0.0, hi=1.0)
#define DOT2(k, word, sel) \
  asm("v_dot2_f32_bf16 %0, %1, %2, %0" : "+v"(acc[k]) : "v"(word), "v"(sel));
#define ACC8(u)                 \
  { DOT2(0, (u).x, selL) DOT2(1, (u).x, selH)  \
    DOT2(2, (u).y, selL) DOT2(3, (u).y, selH)  \
    DOT2(4, (u).z, selL) DOT2(5, (u).z, selH)  \
    DOT2(6, (u).w, selL) DOT2(7, (u).w, selH) }

  for (int nb = ((int)blockIdx.x >> 3) * DUP + dup; nb < nodeblocks; nb += bstride) {
    const int v = nb * 8 + ((int)threadIdx.x >> 5);
    if (v >= N) continue;
    float acc[8] = {0.f, 0.f, 0.f, 0.f, 0.f, 0.f, 0.f, 0.f};
    const int2 se = rowse[v];
    const int end = se.y;
    int j = se.x + sub;
    for (; j + 4 < end; j += 8) {  // 2 edges per iter per sub-stream
      int s0 = csr[j], s1 = csr[j + 4];
      uint4 r0 = *(const uint4*)(base + (size_t)s0 * 64);
      uint4 r1 = *(const uint4*)(base + (size_t)s1 * 64);
      ACC8(r0) ACC8(r1)
    }
    if (j < end) {
      uint4 r = *(const uint4*)(base + (size_t)csr[j] * 64);
      ACC8(r)
    }
    // reduce the 4 sub-streams within each 32-lane group
#pragma unroll
    for (int k = 0; k < 8; ++k) {
      acc[k] += __shfl_xor(acc[k], 8, 32);
      acc[k] += __shfl_xor(acc[k], 16, 32);
    }
    if (sub == 0) {
      {  // self-loop
        uint4 r = *(const uint4*)(base + (size_t)v * 64);
        ACC8(r)
      }
      const float dv = dinv[v];
      float o[8];
      o[0] = dv * acc[0] + bA.x; o[1] = dv * acc[1] + bA.y;
      o[2] = dv * acc[2] + bA.z; o[3] = dv * acc[3] + bA.w;
      o[4] = dv * acc[4] + bB.x; o[5] = dv * acc[5] + bB.y;
      o[6] = dv * acc[6] + bB.z; o[7] = dv * acc[7] + bB.w;
      if constexpr (MODE == 1) {
        u16x8 p;
#pragma unroll
        for (int k = 0; k < 8; ++k) p[k] = f2bf(fmaxf(o[k], 0.f));
        *(u16x8*)(of1 + (size_t)v * C + c0) = p;
      } else {
        *(float4*)(out + (size_t)v * C + c0) = make_float4(o[0], o[1], o[2], o[3]);
        *(float4*)(out + (size_t)v * C + c0 + 4) = make_float4(o[4], o[5], o[6], o[7]);
      }
    }
  }
#undef ACC8
#undef DOT2
}

// ---------------------------------------------------------------------------

extern "C" void kernel_launch(void* const* d_in, const int* in_sizes, int n_in,
                              void* d_out, int out_size, void* d_ws, size_t ws_size,
                              hipStream_t stream) {
  const float* x  = (const float*)d_in[0];
  const void*  ei = d_in[1];
  const float* W1 = (const float*)d_in[2];
  const float* b1 = (const float*)d_in[3];
  const float* W2 = (const float*)d_in[4];
  const float* b2 = (const float*)d_in[5];
  float* out = (float*)d_out;

  const int N = in_sizes[0] / CH1;  // 50000
  const int E = in_sizes[1] / 2;    // 800000

  char* w = (char*)d_ws;
  size_t off = 0;
  auto alloc = [&](size_t bytes) -> void* {
    void* p = w + off;
    off += (bytes + 255) & ~(size_t)255;
    return p;
  };
  int*   deg      = (int*)alloc((size_t)N * 4);
  int*   flag     = (int*)alloc(256);          // flag + gcnt
  int*   e32      = (int*)alloc((size_t)2 * E * 4);
  int2*  rowse    = (int2*)alloc((size_t)N * 8);
  int*   cursor   = (int*)alloc((size_t)N * 4);
  int*   csr      = (int*)alloc((size_t)E * 4);
  float* dinv     = (float*)alloc((size_t)N * 4);
  unsigned short* xh  = (unsigned short*)alloc((size_t)N * CH1 * 2);  // also f1
  unsigned short* g1S = (unsigned short*)alloc((size_t)N * CH1 * 2);  // sliced
  unsigned short* g2S = (unsigned short*)alloc((size_t)N * CH2 * 2);  // sliced
  unsigned short* w1t = (unsigned short*)alloc((size_t)CH1 * CH1 * 2);
  unsigned short* w2t = (unsigned short*)alloc((size_t)CH1 * CH2 * 2);
  int* gcnt = flag + 1;

  const int* srcI = e32;
  const int* dstI = e32 + E;

  dim3 blk(256), blk512(512);
  auto cdiv = [](long long a, long long b) { return (int)((a + b - 1) / b); };
  const int nodeblocks = cdiv(N, 8);   // 6250
  const int n8x = N * CH1 / 8;
  const int AGG_GRID = 2048;           // 8 blocks/CU, slice-affine persistent

  // --- prep: x->bf16, W->W^T bf16, deg/flag/gcnt init ---------------------
  k_prep<<<cdiv((long long)n8x + CH1 * CH1 + CH1 * CH2, 256), blk, 0, stream>>>(
      (const float4*)x, (u16x8*)xh, n8x, W1, w1t, CH1, CH1, W2, w2t, CH1, CH2,
      deg, N, flag, gcnt);

  // --- CSR build (unordered regions) --------------------------------------
  k_detect_i32<<<cdiv(E, 256), blk, 0, stream>>>((const unsigned int*)ei, E, flag);
  k_cvt_deg<<<cdiv(2LL * E, 256), blk, 0, stream>>>(ei, e32, deg, E, flag);
  k_alloc<<<cdiv(N, 256), blk, 0, stream>>>(deg, rowse, cursor, dinv, gcnt, N);
  k_fill<<<cdiv(E, 256), blk, 0, stream>>>(srcI, dstI, cursor, csr, E);

  // --- layer 1: g1 = dinv*(x@W1) sliced ; f1 = relu(dv*sum+b1) bf16 -> xh --
  k_gemm_mfma<CH1><<<cdiv(N, 128), blk512, 0, stream>>>(xh, w1t, dinv, g1S, N, CH1);
  k_agg_slice<CH1, 1><<<AGG_GRID, blk, 0, stream>>>(
      rowse, csr, dinv, g1S, b1, nullptr, xh, N, nodeblocks);

  // --- layer 2: g2 = dinv*(f1@W2) sliced ; out = dv*sum+b2 ----------------
  k_gemm_mfma<CH2><<<cdiv(N, 128), blk512, 0, stream>>>(xh, w2t, dinv, g2S, N, CH1);
  k_agg_slice<CH2, 0><<<AGG_GRID, blk, 0, stream>>>(
      rowse, csr, dinv, g2S, b2, out, nullptr, N, nodeblocks);
}